// Round 3
// baseline (718.142 us; speedup 1.0000x reference)
//
#include <hip/hip_runtime.h>
#include <hip/hip_bf16.h>
#include <stdint.h>

// BinaryTreeLSTM on MI355X (gfx950) — round 3: persistent-B, barrier-free K-loop.
//  - Block owns j-tile (32 cols x 5 gates); weight slice (120KB bf16, frag order)
//    loaded into LDS ONCE per launch. 1 block/CU (LDS-forced), 256 blocks.
//  - A-frags read directly global->VGPR (row=lane&31, k=(lane>>5)*8+i), depth-1
//    prefetch. NO __syncthreads in the K-loop (only one after B staging).
//  - jt = blk>>6, stripe = blk&63: the 4 jt-groups reading the same A rows are
//    congruent mod 8 -> same XCD -> A re-reads served by that XCD's L2.
//  - 4 waves x 2 m-subtiles x 5 gates = 10 f32x16 accums; 32x32x16 bf16 MFMA.
//  - c fp32 (precision), h bf16.

#define BATCH 256
#define TDEPTH 10
#define NTOT 1023
#define HDIM 128
#define NCLS 5
#define GDIM 384
#define NKS 24   // k-steps of 16 across GDIM
#define NJT 4

typedef __bf16 bf16x8 __attribute__((ext_vector_type(8)));
typedef float f32x16 __attribute__((ext_vector_type(16)));

__device__ __forceinline__ float sigmoid_f(float v) { return 1.f / (1.f + __expf(-v)); }
__device__ __forceinline__ float tanh_f(float v) { return 1.f - 2.f / (1.f + __expf(2.f * v)); }

__device__ __forceinline__ void load_lds16(const void* g, void* l) {
  __builtin_amdgcn_global_load_lds((const __attribute__((address_space(1))) unsigned int*)g,
                                   (__attribute__((address_space(3))) unsigned int*)l, 16, 0, 0);
}

// Pack W[g] (128 x 384 fp32) into bf16 fragment order:
// PW[((g*4 + jt)*24 + ks)*64 + lane][8], elem (lane,i) = W[jt*32+(lane&31)][ks*16+(lane>>5)*8+i]
__global__ __launch_bounds__(256) void pack_w(
    const float* __restrict__ W0, const float* __restrict__ W1, const float* __restrict__ W2,
    const float* __restrict__ W3, const float* __restrict__ W4, __bf16* __restrict__ PW)
{
  int t = blockIdx.x * 256 + threadIdx.x;   // 30720 total
  int lane = t & 63;
  int rest = t >> 6;
  int ks = rest % NKS;
  int r2 = rest / NKS;
  int jt = r2 & 3;
  int g = r2 >> 2;
  const float* W = (g == 0) ? W0 : (g == 1) ? W1 : (g == 2) ? W2 : (g == 3) ? W3 : W4;
  const float* s = W + (size_t)(jt * 32 + (lane & 31)) * GDIM + ks * 16 + (lane >> 5) * 8;
  float4 v0 = *(const float4*)s;
  float4 v1 = *(const float4*)(s + 4);
  bf16x8 w;
  w[0] = (__bf16)v0.x; w[1] = (__bf16)v0.y; w[2] = (__bf16)v0.z; w[3] = (__bf16)v0.w;
  w[4] = (__bf16)v1.x; w[5] = (__bf16)v1.y; w[6] = (__bf16)v1.z; w[7] = (__bf16)v1.w;
  *(bf16x8*)(PW + (size_t)t * 8) = w;
}

__global__ __launch_bounds__(256, 1) void level_kernel(
    const float* __restrict__ x, const __bf16* __restrict__ PW,
    const float* __restrict__ bv0, const float* __restrict__ bv1,
    const float* __restrict__ bv2, const float* __restrict__ bv3,
    const float* __restrict__ bv4,
    const __bf16* __restrict__ h_prev, const float* __restrict__ c_prev,
    __bf16* __restrict__ h_out, float* __restrict__ c_out,
    int n, int log2n, int leaf)
{
  __shared__ __bf16 Bs[5 * NKS * 512];   // 122,880 B; chunk (g*nks+ks): 64 lanes x 16B

  const int tid = threadIdx.x;
  const int lane = tid & 63;
  const int wave = tid >> 6;
  const int l31 = lane & 31;
  const int half8 = (lane >> 5) * 8;
  const int jt = blockIdx.x >> 6;        // 0..3
  const int stripe = blockIdx.x & 63;    // 0..63
  const int nks = leaf ? 8 : NKS;
  const int M = BATCH << log2n;

  // ---- stage persistent B slice (once) ----
  for (int c = wave; c < 5 * nks; c += 4) {
    int g = c / nks, ks = c % nks;
    const __bf16* s = PW + (((size_t)(g * NJT + jt) * NKS + ks) * 64 + lane) * 8;
    load_lds16(s, (__bf16*)Bs + (size_t)c * 512);
  }
  __syncthreads();   // only barrier in the kernel

  if (stripe * 256 >= M) return;

  const int j = jt * 32 + l31;
  const float b0 = bv0[j], b1 = bv1[j], b2 = bv2[j], b3 = bv3[j], b4 = bv4[j];
  const int rh = (lane >> 5) * 4;
  const int n2 = 2 * n;

  for (int row0 = stripe * 256 + wave * 64; row0 < M; row0 += 64 * 256) {
    // per-subtile lane A-row pointers
    size_t xp[2], hp[2];
#pragma unroll
    for (int sub = 0; sub < 2; ++sub) {
      int m = row0 + sub * 32 + l31;
      int b = m >> log2n;
      int id = m & (n - 1);
      xp[sub] = ((size_t)b * NTOT + (n - 1) + id) * HDIM;
      hp[sub] = ((size_t)b * n2 + 2 * id) * HDIM;
    }

    auto loadA = [&](int ks, int sub) -> bf16x8 {
      if (ks < 8) {
        const float* s = x + xp[sub] + ks * 16 + half8;
        float4 v0 = *(const float4*)s;
        float4 v1 = *(const float4*)(s + 4);
        bf16x8 w;
        w[0] = (__bf16)v0.x; w[1] = (__bf16)v0.y; w[2] = (__bf16)v0.z; w[3] = (__bf16)v0.w;
        w[4] = (__bf16)v1.x; w[5] = (__bf16)v1.y; w[6] = (__bf16)v1.z; w[7] = (__bf16)v1.w;
        return w;
      } else {
        const __bf16* s = h_prev + hp[sub] + (ks >= 16 ? HDIM : 0) + (ks & 7) * 16 + half8;
        return *(const bf16x8*)s;
      }
    };

    f32x16 acc[2][5];
#pragma unroll
    for (int sub = 0; sub < 2; ++sub)
#pragma unroll
      for (int g = 0; g < 5; ++g)
#pragma unroll
        for (int r = 0; r < 16; ++r) acc[sub][g][r] = 0.f;

    bf16x8 a0 = loadA(0, 0);
    bf16x8 a1 = loadA(0, 1);
    for (int ks = 0; ks < nks; ++ks) {
      int ksn = (ks + 1 < nks) ? ks + 1 : ks;     // clamped prefetch index
      bf16x8 na0 = loadA(ksn, 0);
      bf16x8 na1 = loadA(ksn, 1);
#pragma unroll
      for (int g = 0; g < 5; ++g) {
        bf16x8 bb = *(const bf16x8*)((const __bf16*)Bs + ((size_t)(g * nks + ks) * 512) + lane * 8);
        acc[0][g] = __builtin_amdgcn_mfma_f32_32x32x16_bf16(a0, bb, acc[0][g], 0, 0, 0);
        acc[1][g] = __builtin_amdgcn_mfma_f32_32x32x16_bf16(a1, bb, acc[1][g], 0, 0, 0);
      }
      a0 = na0; a1 = na1;
    }

    // ---- epilogue: D layout col(j)=lane&31, row = (r&3)+8*(r>>2)+4*(lane>>5)
#pragma unroll
    for (int sub = 0; sub < 2; ++sub) {
      const int mb = row0 + sub * 32 + rh;
#pragma unroll
      for (int r = 0; r < 16; ++r) {
        int m = mb + (r & 3) + 8 * (r >> 2);
        int b = m >> log2n;
        int id = m & (n - 1);
        float gi = sigmoid_f(acc[sub][0][r] + b0);
        float gl = sigmoid_f(acc[sub][1][r] + b1);
        float gr = sigmoid_f(acc[sub][2][r] + b2);
        float go = sigmoid_f(acc[sub][3][r] + b3);
        float gu = tanh_f(acc[sub][4][r] + b4);
        float cv = gi * gu;
        if (!leaf) {
          size_t cb = ((size_t)b * n2 + 2 * id) * HDIM + j;
          cv += gl * c_prev[cb] + gr * c_prev[cb + HDIM];
        }
        size_t ob = ((size_t)b * n + id) * HDIM + j;
        c_out[ob] = cv;
        h_out[ob] = (__bf16)(go * tanh_f(cv));
      }
    }
  }
}

__global__ __launch_bounds__(256) void cls_kernel(
    const __bf16* __restrict__ hroot, const float* __restrict__ Wc,
    const float* __restrict__ bc, float* __restrict__ out)
{
  int t = blockIdx.x * blockDim.x + threadIdx.x;
  if (t >= BATCH * NCLS) return;
  int b = t / NCLS, ci = t % NCLS;
  float s = bc[ci];
#pragma unroll 4
  for (int jj = 0; jj < HDIM; ++jj)
    s += (float)hroot[b * HDIM + jj] * Wc[ci * HDIM + jj];
  out[t] = s;
}

extern "C" void kernel_launch(void* const* d_in, const int* in_sizes, int n_in,
                              void* d_out, int out_size, void* d_ws, size_t ws_size,
                              hipStream_t stream) {
  const float* x  = (const float*)d_in[0];
  const float* W[5]  = {(const float*)d_in[1], (const float*)d_in[3], (const float*)d_in[5],
                        (const float*)d_in[7], (const float*)d_in[9]};
  const float* bv[5] = {(const float*)d_in[2], (const float*)d_in[4], (const float*)d_in[6],
                        (const float*)d_in[8], (const float*)d_in[10]};
  const float* Wcls = (const float*)d_in[11];
  const float* bcls = (const float*)d_in[12];

  uint8_t* ws = (uint8_t*)d_ws;
  __bf16* hb[2] = {(__bf16*)ws, (__bf16*)(ws + 33554432)};             // 32MB + 16MB
  float*  cb[2] = {(float*)(ws + 50331648), (float*)(ws + 117440512)}; // 64MB + 32MB
  __bf16* PW = (__bf16*)(ws + 150994944);                              // 480KB

  pack_w<<<120, 256, 0, stream>>>(W[0], W[1], W[2], W[3], W[4], PW);

  for (int d = TDEPTH - 1; d >= 0; --d) {
    int n = 1 << d;
    int wi = (TDEPTH - 1 - d) & 1;
    int ri = wi ^ 1;
    int leaf = (d == TDEPTH - 1) ? 1 : 0;
    level_kernel<<<256, 256, 0, stream>>>(
        x, PW, bv[0], bv[1], bv[2], bv[3], bv[4],
        hb[ri], cb[ri], hb[wi], cb[wi], n, d, leaf);
  }
  cls_kernel<<<(BATCH * NCLS + 255) / 256, 256, 0, stream>>>(hb[1], Wcls, bcls, (float*)d_out);
}